// Round 1
// baseline (927.029 us; speedup 1.0000x reference)
//
#include <hip/hip_runtime.h>
#include <hip/hip_bf16.h>

typedef __attribute__((ext_vector_type(4))) float f32x4;
typedef __attribute__((ext_vector_type(8))) short bf16x8;

#define GL2LDS16(g, l) __builtin_amdgcn_global_load_lds(                     \
    (const __attribute__((address_space(1))) void*)(g),                      \
    (__attribute__((address_space(3))) void*)(l), 16, 0, 0)

__device__ __forceinline__ float b2f(unsigned short u) {
  union { unsigned int i; float f; } x;
  x.i = ((unsigned int)u) << 16;
  return x.f;
}
__device__ __forceinline__ unsigned short f2b(float f) {
  __hip_bfloat16 h = __float2bfloat16(f);
  return *reinterpret_cast<unsigned short*>(&h);
}

// ---------------- cvt: x fp32 -> bf16 (vectorized) --------------------------
__global__ __launch_bounds__(256) void cvt_x(
    const float4* __restrict__ x, ushort4* __restrict__ xb, int n4)
{
  for (int i = blockIdx.x * 256 + threadIdx.x; i < n4; i += gridDim.x * 256) {
    float4 v = x[i];
    ushort4 o;
    o.x = f2b(v.x); o.y = f2b(v.y); o.z = f2b(v.z); o.w = f2b(v.w);
    xb[i] = o;
  }
}

// ---------------- prep: transpose weights + pre-swizzle bias ----------------
// biasC layout: [h][mt*6+ct][lane][r] bf16, row=mt*16+quad*4+r, col=ct*16+(lane&15)
// padded key columns (col>=84) get -1e30 so exp() kills them exactly.
__global__ __launch_bounds__(256) void prep_k(
    const float* __restrict__ Wqkv,    // [256][768] fp32
    const float* __restrict__ Wproj,   // [256][256] fp32
    const float* __restrict__ btab,    // [207][8]   fp32
    const int* __restrict__ relidx,    // [84][84]
    __hip_bfloat16* __restrict__ WqkvT,   // [768][256] bf16
    __hip_bfloat16* __restrict__ WprojT,  // [256][256] bf16
    __hip_bfloat16* __restrict__ biasC)   // [8][36][64][4] bf16
{
  int idx = blockIdx.x * 256 + threadIdx.x;
  if (idx < 196608) {
    int n = idx >> 8, k = idx & 255;
    WqkvT[idx] = __float2bfloat16(Wqkv[k * 768 + n]);
  } else if (idx < 262144) {
    int i = idx - 196608;
    int n = i >> 8, k = i & 255;
    WprojT[i] = __float2bfloat16(Wproj[k * 256 + n]);
  } else if (idx < 335872) {
    int i = idx - 262144;
    int r = i & 3, lane = (i >> 2) & 63, tile = i >> 8;
    int ct = tile % 6, mt = (tile / 6) % 6, h = tile / 36;
    int row = mt * 16 + ((lane >> 4) << 2) + r;
    int col = ct * 16 + (lane & 15);
    float v;
    if (col >= 84)      v = -1e30f;   // padded key -> softmax weight 0
    else if (row >= 84) v = 0.0f;     // padded query row -> never stored
    else                v = btab[relidx[row * 84 + col] * 8 + h];
    biasC[i] = __float2bfloat16(v);
  }
}

// ---------------- GEMM: C[M][N] = A[M][256] @ Bt[N][256]^T + bias ----------
// m97 structure: 128x128 block tile, 4 waves of 4x4 16x16 tiles, BK=32,
// global_load_lds width-16 staging (wave-uniform LDS base + lane*16).
// OUTF=1 -> fp32 C, OUTF=0 -> bf16 C.
template <int OUTF>
__global__ __launch_bounds__(256, 2) void gemm_bt(
    const __hip_bfloat16* __restrict__ A,
    const __hip_bfloat16* __restrict__ Bt,
    const float* __restrict__ bias,
    void* __restrict__ Cv,
    const int N)
{
  __shared__ __align__(16) __hip_bfloat16 As[128 * 32];
  __shared__ __align__(16) __hip_bfloat16 Bs[128 * 32];
  const int t = threadIdx.x;
  const int w = t >> 6, lane = t & 63;
  const int lane15 = lane & 15, quad = lane >> 4;
  const int m0 = blockIdx.x * 128, n0 = blockIdx.y * 128;
  const int wm = (w >> 1) * 64, wn = (w & 1) * 64;
  const int srow = w * 16 + (lane >> 2);   // staged row within 64-row half
  const int scol = (lane & 3) * 8;         // element offset within 32-wide K slab
  const __hip_bfloat16* gA = A + (size_t)(m0 + srow) * 256 + scol;
  const __hip_bfloat16* gB = Bt + (size_t)(n0 + srow) * 256 + scol;
  __hip_bfloat16* lA = As + w * 16 * 32;   // wave-uniform LDS base
  __hip_bfloat16* lB = Bs + w * 16 * 32;
  f32x4 acc[4][4] = {};
#pragma unroll 1
  for (int kk = 0; kk < 8; ++kk) {
    GL2LDS16(gA + kk * 32, lA);
    GL2LDS16(gA + 64 * 256 + kk * 32, lA + 64 * 32);
    GL2LDS16(gB + kk * 32, lB);
    GL2LDS16(gB + 64 * 256 + kk * 32, lB + 64 * 32);
    __syncthreads();  // compiler inserts vmcnt(0) drain before barrier
    bf16x8 af[4], bfr[4];
#pragma unroll
    for (int i = 0; i < 4; ++i)
      af[i] = *(const bf16x8*)(As + (wm + i * 16 + lane15) * 32 + quad * 8);
#pragma unroll
    for (int j = 0; j < 4; ++j)
      bfr[j] = *(const bf16x8*)(Bs + (wn + j * 16 + lane15) * 32 + quad * 8);
#pragma unroll
    for (int i = 0; i < 4; ++i)
#pragma unroll
      for (int j = 0; j < 4; ++j)
        acc[i][j] = __builtin_amdgcn_mfma_f32_16x16x32_bf16(af[i], bfr[j], acc[i][j], 0, 0, 0);
    __syncthreads();
  }
#pragma unroll
  for (int j = 0; j < 4; ++j) {
    const int col = n0 + wn + j * 16 + lane15;
    const float bv = bias[col];
#pragma unroll
    for (int i = 0; i < 4; ++i) {
      const int row = m0 + wm + i * 16 + quad * 4;
#pragma unroll
      for (int r = 0; r < 4; ++r) {
        const size_t o = (size_t)(row + r) * N + col;
        if (OUTF) ((float*)Cv)[o] = acc[i][j][r] + bv;
        else ((__hip_bfloat16*)Cv)[o] = __float2bfloat16(acc[i][j][r] + bv);
      }
    }
  }
}

// ---------------- fused attention (softmax(QK^T*s + bias) @ V) -------------
// v2: per-mt streaming. QK^T has no K-loop (head_dim=32 = 1 MFMA) and softmax
// is independent per 16-row block mt, so we never hold S[6][6] (144 VGPRs) or
// a 96-row P slab (80 KB LDS). Per mt: 6 QK MFMAs -> softmax -> 16x104 P slab
// -> 6 PV MFMAs -> store. S:24 VGPR, O:8, P:13 KB. Total LDS 40 KB.
// Occupancy 1 block/CU -> 2-3 blocks/CU; latency chains hidden by TLP.
// 1 block per batch element; wave w handles heads w and w+4. All LDS per-wave
// => no __syncthreads. Tokens padded 84->96; padded key cols killed by -1e30
// bias; padded query rows computed but never stored.
__global__ __launch_bounds__(256, 3) void attn_k(
    const __hip_bfloat16* __restrict__ qkv,    // [172048][768] (pad rows for last-batch frag reads)
    const __hip_bfloat16* __restrict__ biasC,  // [8][36][64][4]
    __hip_bfloat16* __restrict__ aout)         // [172032][256]
{
  __shared__ __align__(16) __hip_bfloat16 Pb[4][16 * 104];
  __shared__ __align__(16) __hip_bfloat16 Vt[4][32 * 104];
  const int b = blockIdx.x;
  const int t = threadIdx.x;
  const int w = t >> 6, lane = t & 63;
  const int lane15 = lane & 15, quad = lane >> 4;
  const __hip_bfloat16* base = qkv + (size_t)b * (84 * 768);
  __hip_bfloat16* Pw = Pb[w];
  __hip_bfloat16* Vw = Vt[w];
  const float scale = 0.10910894511799619f;  // 84^-0.5

  // zero V^T pad columns (key tokens 84..95): P=0 there, but 0*garbage traps us
  for (int i = lane; i < 32 * 12; i += 64) {
    int d = i / 12, tok = 84 + (i % 12);
    Vw[d * 104 + tok] = __float2bfloat16(0.0f);
  }

  for (int hi = 0; hi < 2; ++hi) {
    const int h = w + 4 * hi;
    // stage V^T: Vw[d][tok] = V[tok][d]
    for (int i = lane; i < 84 * 32; i += 64) {
      int tok = i >> 5, d = i & 31;
      Vw[d * 104 + tok] = base[(size_t)tok * 768 + 512 + h * 32 + d];
    }
    // Q/K fragments: contiguous 16B chunks straight from global (overlap the
    // V-staging latency)
    bf16x8 qa[6], kb[6];
#pragma unroll
    for (int i = 0; i < 6; ++i)
      qa[i] = *(const bf16x8*)(base + (size_t)(i * 16 + lane15) * 768 + h * 32 + quad * 8);
#pragma unroll
    for (int j = 0; j < 6; ++j)
      kb[j] = *(const bf16x8*)(base + (size_t)(j * 16 + lane15) * 768 + 256 + h * 32 + quad * 8);
    // V^T fragments for PV, hoisted across the mt loop (read LDS once/head)
    bf16x8 vb[3][2];
#pragma unroll
    for (int kk = 0; kk < 3; ++kk) {
      vb[kk][0] = *(const bf16x8*)(Vw + lane15 * 104 + kk * 32 + quad * 8);
      vb[kk][1] = *(const bf16x8*)(Vw + (16 + lane15) * 104 + kk * 32 + quad * 8);
    }

    const unsigned short* bC = (const unsigned short*)biasC + (size_t)h * 9216 + lane * 4;
#pragma unroll 1
    for (int mt = 0; mt < 6; ++mt) {
      // QK^T row-block: 6 independent MFMAs (head_dim 32 = single K step)
      f32x4 S[6] = {};
#pragma unroll
      for (int ct = 0; ct < 6; ++ct)
        S[ct] = __builtin_amdgcn_mfma_f32_16x16x32_bf16(qa[mt], kb[ct], S[ct], 0, 0, 0);

      // softmax: a row of S spans the 16 lanes of a quad-group (col=lane&15)
      f32x4 mx = {-3.0e38f, -3.0e38f, -3.0e38f, -3.0e38f};
#pragma unroll
      for (int ct = 0; ct < 6; ++ct) {
        ushort4 bb = *(const ushort4*)(bC + (mt * 6 + ct) * 256);
        f32x4 tv;
        tv[0] = S[ct][0] * scale + b2f(bb.x);
        tv[1] = S[ct][1] * scale + b2f(bb.y);
        tv[2] = S[ct][2] * scale + b2f(bb.z);
        tv[3] = S[ct][3] * scale + b2f(bb.w);
        S[ct] = tv;
        mx[0] = fmaxf(mx[0], tv[0]); mx[1] = fmaxf(mx[1], tv[1]);
        mx[2] = fmaxf(mx[2], tv[2]); mx[3] = fmaxf(mx[3], tv[3]);
      }
#pragma unroll
      for (int off = 1; off < 16; off <<= 1) {
#pragma unroll
        for (int r = 0; r < 4; ++r)
          mx[r] = fmaxf(mx[r], __shfl_xor(mx[r], off, 64));
      }
      f32x4 sm = {0.f, 0.f, 0.f, 0.f};
#pragma unroll
      for (int ct = 0; ct < 6; ++ct) {
#pragma unroll
        for (int r = 0; r < 4; ++r) {
          float p = __expf(S[ct][r] - mx[r]);
          sm[r] += p;
          // C-layout -> row-major P~ slab in per-wave LDS (A-operand for PV)
          Pw[(quad * 4 + r) * 104 + ct * 16 + lane15] = __float2bfloat16(p);
        }
      }
#pragma unroll
      for (int off = 1; off < 16; off <<= 1) {
#pragma unroll
        for (int r = 0; r < 4; ++r)
          sm[r] += __shfl_xor(sm[r], off, 64);
      }
      f32x4 inv;
      inv[0] = 1.0f / sm[0]; inv[1] = 1.0f / sm[1];
      inv[2] = 1.0f / sm[2]; inv[3] = 1.0f / sm[3];

      // P~ @ V for this row-block (K = 96 over 3 slabs of 32)
      f32x4 O0 = {}, O1 = {};
#pragma unroll
      for (int kk = 0; kk < 3; ++kk) {
        bf16x8 pa = *(const bf16x8*)(Pw + lane15 * 104 + kk * 32 + quad * 8);
        O0 = __builtin_amdgcn_mfma_f32_16x16x32_bf16(pa, vb[kk][0], O0, 0, 0, 0);
        O1 = __builtin_amdgcn_mfma_f32_16x16x32_bf16(pa, vb[kk][1], O1, 0, 0, 0);
      }
      // normalize + store rows < 84
#pragma unroll
      for (int r = 0; r < 4; ++r) {
        int row = mt * 16 + quad * 4 + r;
        if (row < 84) {
          size_t o = (size_t)(b * 84 + row) * 256 + h * 32 + lane15;
          aout[o]      = __float2bfloat16(O0[r] * inv[r]);
          aout[o + 16] = __float2bfloat16(O1[r] * inv[r]);
        }
      }
    }
  }
}

// ---------------------------------------------------------------------------
extern "C" void kernel_launch(void* const* d_in, const int* in_sizes, int n_in,
                              void* d_out, int out_size, void* d_ws, size_t ws_size,
                              hipStream_t stream) {
  const float* x     = (const float*)d_in[0];
  const float* Wqkv  = (const float*)d_in[1];
  const float* bqkv  = (const float*)d_in[2];
  const float* Wproj = (const float*)d_in[3];
  const float* bproj = (const float*)d_in[4];
  const float* btab  = (const float*)d_in[5];
  const int* relidx  = (const int*)d_in[6];
  float* out = (float*)d_out;

  char* ws = (char*)d_ws;
  const size_t QKV_BYTES  = (size_t)172048 * 768 * 2;   // 264,265,728 (pad rows)
  const size_t REG2_BYTES = (size_t)172032 * 256 * 2;   //  88,080,384 (xb then aout)
  const size_t SMALL_BYTES = (size_t)(768 * 256 + 256 * 256 + 73728) * 2;
  if (ws_size < QKV_BYTES + REG2_BYTES + SMALL_BYTES) return;  // 353,017,856 B

  __hip_bfloat16* qkv  = (__hip_bfloat16*)ws;
  __hip_bfloat16* reg2 = (__hip_bfloat16*)(ws + QKV_BYTES);   // xb during GEMM-1, aout after
  __hip_bfloat16* WqkvT  = (__hip_bfloat16*)(ws + QKV_BYTES + REG2_BYTES);
  __hip_bfloat16* WprojT = WqkvT + 768 * 256;
  __hip_bfloat16* biasC  = WprojT + 256 * 256;

  cvt_x<<<1024, 256, 0, stream>>>((const float4*)x, (ushort4*)reg2, 172032 * 256 / 4);
  prep_k<<<1312, 256, 0, stream>>>(Wqkv, Wproj, btab, relidx, WqkvT, WprojT, biasC);
  gemm_bt<0><<<dim3(1344, 6), 256, 0, stream>>>(reg2, WqkvT, bqkv, qkv, 768);
  attn_k<<<2048, 256, 0, stream>>>(qkv, biasC, reg2);
  gemm_bt<1><<<dim3(1344, 2), 256, 0, stream>>>(reg2, WprojT, bproj, out, 256);
}

// Round 2
// 865.491 us; speedup vs baseline: 1.0711x; 1.0711x over previous
//
#include <hip/hip_runtime.h>
#include <hip/hip_bf16.h>

typedef __attribute__((ext_vector_type(4))) float f32x4;
typedef __attribute__((ext_vector_type(8))) short bf16x8;

#define GL2LDS16(g, l) __builtin_amdgcn_global_load_lds(                     \
    (const __attribute__((address_space(1))) void*)(g),                      \
    (__attribute__((address_space(3))) void*)(l), 16, 0, 0)

__device__ __forceinline__ float b2f(unsigned short u) {
  union { unsigned int i; float f; } x;
  x.i = ((unsigned int)u) << 16;
  return x.f;
}
__device__ __forceinline__ unsigned short f2b(float f) {
  __hip_bfloat16 h = __float2bfloat16(f);
  return *reinterpret_cast<unsigned short*>(&h);
}

// ---------------- cvt: x fp32 -> bf16 (vectorized) --------------------------
__global__ __launch_bounds__(256) void cvt_x(
    const float4* __restrict__ x, ushort4* __restrict__ xb, int n4)
{
  for (int i = blockIdx.x * 256 + threadIdx.x; i < n4; i += gridDim.x * 256) {
    float4 v = x[i];
    ushort4 o;
    o.x = f2b(v.x); o.y = f2b(v.y); o.z = f2b(v.z); o.w = f2b(v.w);
    xb[i] = o;
  }
}

// ---------------- prep: transpose weights + pre-swizzle bias + pads ---------
// biasC layout: [h][mt*6+ct][lane][r] bf16, row=mt*16+quad*4+r, col=ct*16+(lane&15)
// padded key columns (col>=84) get -1e30 so exp() kills them exactly.
// Also zeroes vT tok-pads (84..95) and qkv pad rows (172032..172047).
__global__ __launch_bounds__(256) void prep_k(
    const float* __restrict__ Wqkv,    // [256][768] fp32
    const float* __restrict__ Wproj,   // [256][256] fp32
    const float* __restrict__ btab,    // [207][8]   fp32
    const int* __restrict__ relidx,    // [84][84]
    __hip_bfloat16* __restrict__ WqkvT,   // [768][256] bf16
    __hip_bfloat16* __restrict__ WprojT,  // [256][256] bf16
    __hip_bfloat16* __restrict__ biasC,   // [8][36][64][4] bf16
    __hip_bfloat16* __restrict__ vT,      // [2048*8*32][96] bf16
    __hip_bfloat16* __restrict__ qkvp)    // qkv buffer (for pad-row zeroing)
{
  int idx = blockIdx.x * 256 + threadIdx.x;
  if (idx < 196608) {
    int n = idx >> 8, k = idx & 255;
    WqkvT[idx] = __float2bfloat16(Wqkv[k * 768 + n]);
  } else if (idx < 262144) {
    int i = idx - 196608;
    int n = i >> 8, k = i & 255;
    WprojT[i] = __float2bfloat16(Wproj[k * 256 + n]);
  } else if (idx < 335872) {
    int i = idx - 262144;
    int r = i & 3, lane = (i >> 2) & 63, tile = i >> 8;
    int ct = tile % 6, mt = (tile / 6) % 6, h = tile / 36;
    int row = mt * 16 + ((lane >> 4) << 2) + r;
    int col = ct * 16 + (lane & 15);
    float v;
    if (col >= 84)      v = -1e30f;   // padded key -> softmax weight 0
    else if (row >= 84) v = 0.0f;     // padded query row -> never stored
    else                v = btab[relidx[row * 84 + col] * 8 + h];
    biasC[i] = __float2bfloat16(v);
  } else if (idx < 860160) {
    // zero vT tok-pads 84..95 for every (b,h,d) row (stride 96)
    size_t i = idx - 335872;              // [0, 524288)
    __hip_bfloat16* p = vT + i * 96;
    *(ushort4*)(p + 84) = make_ushort4(0, 0, 0, 0);        // elems 84..87 (8B)
    *(uint4*)(p + 88) = make_uint4(0, 0, 0, 0);            // elems 88..95 (16B)
  } else if (idx < 861184) {
    // zero qkv pad rows 172032..172047 (8192 elems, 16B per thread)
    size_t i = idx - 860160;              // [0, 1024)
    *(uint4*)(qkvp + (size_t)172032 * 512 + i * 8) = make_uint4(0, 0, 0, 0);
  }
}

// ---------------- GEMM: C[M][N] = A[M][256] @ Bt[N][256]^T + bias ----------
// m97 structure: 128x128 block tile, 4 waves of 4x4 16x16 tiles, BK=32,
// global_load_lds width-16 staging (wave-uniform LDS base + lane*16).
// MODE 0: A row-major 256 (xb); out = qkv512 (cols<512, bf16) + vT redirect
//         (cols>=512 -> vT[b*256 + (col-512)][96] at tok=row%84).
// MODE 1: A head-major [kk][172032][32] (attn out); out fp32 row-major 256.
template <int MODE>
__global__ __launch_bounds__(256, 2) void gemm_bt(
    const __hip_bfloat16* __restrict__ A,
    const __hip_bfloat16* __restrict__ Bt,
    const float* __restrict__ bias,
    void* __restrict__ Cv,
    __hip_bfloat16* __restrict__ vT)
{
  __shared__ __align__(16) __hip_bfloat16 As[128 * 32];
  __shared__ __align__(16) __hip_bfloat16 Bs[128 * 32];
  const int t = threadIdx.x;
  const int w = t >> 6, lane = t & 63;
  const int lane15 = lane & 15, quad = lane >> 4;
  const int m0 = blockIdx.x * 128, n0 = blockIdx.y * 128;
  const int wm = (w >> 1) * 64, wn = (w & 1) * 64;
  const int srow = w * 16 + (lane >> 2);   // staged row within 64-row half
  const int scol = (lane & 3) * 8;         // element offset within 32-wide K slab
  const __hip_bfloat16* gA = A + (size_t)(m0 + srow) * 256 + scol;
  const __hip_bfloat16* gB = Bt + (size_t)(n0 + srow) * 256 + scol;
  __hip_bfloat16* lA = As + w * 16 * 32;   // wave-uniform LDS base
  __hip_bfloat16* lB = Bs + w * 16 * 32;
  f32x4 acc[4][4] = {};
#pragma unroll 1
  for (int kk = 0; kk < 8; ++kk) {
    if (MODE == 0) {
      GL2LDS16(gA + kk * 32, lA);
      GL2LDS16(gA + 64 * 256 + kk * 32, lA + 64 * 32);
    } else {
      const __hip_bfloat16* gAk = A + ((size_t)kk * 172032 + m0 + srow) * 32 + scol;
      GL2LDS16(gAk, lA);
      GL2LDS16(gAk + 64 * 32, lA + 64 * 32);
    }
    GL2LDS16(gB + kk * 32, lB);
    GL2LDS16(gB + 64 * 256 + kk * 32, lB + 64 * 32);
    __syncthreads();  // compiler inserts vmcnt(0) drain before barrier
    bf16x8 af[4], bfr[4];
#pragma unroll
    for (int i = 0; i < 4; ++i)
      af[i] = *(const bf16x8*)(As + (wm + i * 16 + lane15) * 32 + quad * 8);
#pragma unroll
    for (int j = 0; j < 4; ++j)
      bfr[j] = *(const bf16x8*)(Bs + (wn + j * 16 + lane15) * 32 + quad * 8);
#pragma unroll
    for (int i = 0; i < 4; ++i)
#pragma unroll
      for (int j = 0; j < 4; ++j)
        acc[i][j] = __builtin_amdgcn_mfma_f32_16x16x32_bf16(af[i], bfr[j], acc[i][j], 0, 0, 0);
    __syncthreads();
  }
  if (MODE == 1) {
#pragma unroll
    for (int j = 0; j < 4; ++j) {
      const int col = n0 + wn + j * 16 + lane15;
      const float bv = bias[col];
#pragma unroll
      for (int i = 0; i < 4; ++i) {
        const int row = m0 + wm + i * 16 + quad * 4;
#pragma unroll
        for (int r = 0; r < 4; ++r)
          ((float*)Cv)[(size_t)(row + r) * 256 + col] = acc[i][j][r] + bv;
      }
    }
  } else if (blockIdx.y < 4) {
    // q,k columns -> qkv buffer, stride 512
#pragma unroll
    for (int j = 0; j < 4; ++j) {
      const int col = n0 + wn + j * 16 + lane15;
      const float bv = bias[col];
#pragma unroll
      for (int i = 0; i < 4; ++i) {
        const int row = m0 + wm + i * 16 + quad * 4;
#pragma unroll
        for (int r = 0; r < 4; ++r)
          ((__hip_bfloat16*)Cv)[(size_t)(row + r) * 512 + col] = __float2bfloat16(acc[i][j][r] + bv);
      }
    }
  } else {
    // v columns -> transposed vT[b*256 + cd][96] at tok
#pragma unroll
    for (int j = 0; j < 4; ++j) {
      const int col = n0 + wn + j * 16 + lane15;
      const float bv = bias[col];
      const int cd = col - 512;  // h*32+d in [0,256)
#pragma unroll
      for (int i = 0; i < 4; ++i) {
        const int row = m0 + wm + i * 16 + quad * 4;
#pragma unroll
        for (int r = 0; r < 4; ++r) {
          const unsigned rowg = row + r;
          const unsigned bq = rowg / 84u;         // magic-mul (const divisor)
          const unsigned tok = rowg - bq * 84u;
          vT[((size_t)bq * 256 + cd) * 96 + tok] = __float2bfloat16(acc[i][j][r] + bv);
        }
      }
    }
  }
}

// ---------------- fused attention (softmax(QK^T*s + bias) @ V) -------------
// v3: grid (2048,2); wave w handles head w+4*blockIdx.y (1 head/wave).
// No V staging: V^T fragments load directly from pre-transposed vT (16B
// vector loads). Only Pw (16x104) per wave in LDS -> 13.3 KB/block.
// Output head-major aout[h][172032][32]: each wave fully owns every 64B
// sector it writes (no cross-wave partial-line write amplification).
__global__ __launch_bounds__(256, 5) void attn_k(
    const __hip_bfloat16* __restrict__ qkv,    // [172048][512] q,k (pad rows zeroed)
    const __hip_bfloat16* __restrict__ biasC,  // [8][36][64][4]
    const __hip_bfloat16* __restrict__ vT,     // [2048*8*32][96]
    __hip_bfloat16* __restrict__ aout)         // [8][172032][32] head-major
{
  __shared__ __align__(16) __hip_bfloat16 Pb[4][16 * 104];
  const int b = blockIdx.x;
  const int t = threadIdx.x;
  const int w = t >> 6, lane = t & 63;
  const int lane15 = lane & 15, quad = lane >> 4;
  const int h = w + 4 * blockIdx.y;
  const __hip_bfloat16* base = qkv + (size_t)b * (84 * 512);
  __hip_bfloat16* Pw = Pb[w];
  const float scale = 0.10910894511799619f;  // 84^-0.5

  // Q/K fragments: contiguous 16B chunks straight from global
  bf16x8 qa[6], kb[6], vb[3][2];
#pragma unroll
  for (int i = 0; i < 6; ++i)
    qa[i] = *(const bf16x8*)(base + (size_t)(i * 16 + lane15) * 512 + h * 32 + quad * 8);
#pragma unroll
  for (int j = 0; j < 6; ++j)
    kb[j] = *(const bf16x8*)(base + (size_t)(j * 16 + lane15) * 512 + 256 + h * 32 + quad * 8);
  // V^T fragments straight from vT (tok pads 84..95 are zeroed)
  const __hip_bfloat16* vbase = vT + (size_t)(b * 256 + h * 32) * 96;
#pragma unroll
  for (int kk = 0; kk < 3; ++kk) {
    vb[kk][0] = *(const bf16x8*)(vbase + (size_t)lane15 * 96 + kk * 32 + quad * 8);
    vb[kk][1] = *(const bf16x8*)(vbase + (size_t)(16 + lane15) * 96 + kk * 32 + quad * 8);
  }

  const unsigned short* bC = (const unsigned short*)biasC + (size_t)h * 9216 + lane * 4;
#pragma unroll 1
  for (int mt = 0; mt < 6; ++mt) {
    // QK^T row-block: 6 independent MFMAs (head_dim 32 = single K step)
    f32x4 S[6] = {};
#pragma unroll
    for (int ct = 0; ct < 6; ++ct)
      S[ct] = __builtin_amdgcn_mfma_f32_16x16x32_bf16(qa[mt], kb[ct], S[ct], 0, 0, 0);

    // softmax: a row of S spans the 16 lanes of a quad-group (col=lane&15)
    f32x4 mx = {-3.0e38f, -3.0e38f, -3.0e38f, -3.0e38f};
#pragma unroll
    for (int ct = 0; ct < 6; ++ct) {
      ushort4 bb = *(const ushort4*)(bC + (mt * 6 + ct) * 256);
      f32x4 tv;
      tv[0] = S[ct][0] * scale + b2f(bb.x);
      tv[1] = S[ct][1] * scale + b2f(bb.y);
      tv[2] = S[ct][2] * scale + b2f(bb.z);
      tv[3] = S[ct][3] * scale + b2f(bb.w);
      S[ct] = tv;
      mx[0] = fmaxf(mx[0], tv[0]); mx[1] = fmaxf(mx[1], tv[1]);
      mx[2] = fmaxf(mx[2], tv[2]); mx[3] = fmaxf(mx[3], tv[3]);
    }
#pragma unroll
    for (int off = 1; off < 16; off <<= 1) {
#pragma unroll
      for (int r = 0; r < 4; ++r)
        mx[r] = fmaxf(mx[r], __shfl_xor(mx[r], off, 64));
    }
    f32x4 sm = {0.f, 0.f, 0.f, 0.f};
#pragma unroll
    for (int ct = 0; ct < 6; ++ct) {
#pragma unroll
      for (int r = 0; r < 4; ++r) {
        float p = __expf(S[ct][r] - mx[r]);
        sm[r] += p;
        // C-layout -> row-major P~ slab in per-wave LDS (A-operand for PV)
        Pw[(quad * 4 + r) * 104 + ct * 16 + lane15] = __float2bfloat16(p);
      }
    }
#pragma unroll
    for (int off = 1; off < 16; off <<= 1) {
#pragma unroll
      for (int r = 0; r < 4; ++r)
        sm[r] += __shfl_xor(sm[r], off, 64);
    }
    f32x4 inv;
    inv[0] = 1.0f / sm[0]; inv[1] = 1.0f / sm[1];
    inv[2] = 1.0f / sm[2]; inv[3] = 1.0f / sm[3];

    // P~ @ V for this row-block (K = 96 over 3 slabs of 32)
    f32x4 O0 = {}, O1 = {};
#pragma unroll
    for (int kk = 0; kk < 3; ++kk) {
      bf16x8 pa = *(const bf16x8*)(Pw + lane15 * 104 + kk * 32 + quad * 8);
      O0 = __builtin_amdgcn_mfma_f32_16x16x32_bf16(pa, vb[kk][0], O0, 0, 0, 0);
      O1 = __builtin_amdgcn_mfma_f32_16x16x32_bf16(pa, vb[kk][1], O1, 0, 0, 0);
    }
    // normalize + store rows < 84 (head-major: wave owns its 64B sectors)
#pragma unroll
    for (int r = 0; r < 4; ++r) {
      int row = mt * 16 + quad * 4 + r;
      if (row < 84) {
        size_t o = ((size_t)h * 172032 + (size_t)b * 84 + row) * 32 + lane15;
        aout[o]      = __float2bfloat16(O0[r] * inv[r]);
        aout[o + 16] = __float2bfloat16(O1[r] * inv[r]);
      }
    }
  }
}

// ---------------------------------------------------------------------------
extern "C" void kernel_launch(void* const* d_in, const int* in_sizes, int n_in,
                              void* d_out, int out_size, void* d_ws, size_t ws_size,
                              hipStream_t stream) {
  const float* x     = (const float*)d_in[0];
  const float* Wqkv  = (const float*)d_in[1];
  const float* bqkv  = (const float*)d_in[2];
  const float* Wproj = (const float*)d_in[3];
  const float* bproj = (const float*)d_in[4];
  const float* btab  = (const float*)d_in[5];
  const int* relidx  = (const int*)d_in[6];
  float* out = (float*)d_out;

  char* ws = (char*)d_ws;
  const size_t QKV_BYTES  = (size_t)172048 * 512 * 2;   // 176,177,152 (q,k only + pad rows)
  const size_t REG2_BYTES = (size_t)172032 * 256 * 2;   //  88,080,384 (xb then aout head-major)
  const size_t SMALL_BYTES = (size_t)(768 * 256 + 256 * 256 + 73728) * 2;
  if (ws_size < QKV_BYTES + REG2_BYTES + SMALL_BYTES) return;  // 264,929,280 B

  __hip_bfloat16* qkv  = (__hip_bfloat16*)ws;
  __hip_bfloat16* reg2 = (__hip_bfloat16*)(ws + QKV_BYTES);   // xb during GEMM-1, aout after
  __hip_bfloat16* WqkvT  = (__hip_bfloat16*)(ws + QKV_BYTES + REG2_BYTES);
  __hip_bfloat16* WprojT = WqkvT + 768 * 256;
  __hip_bfloat16* biasC  = WprojT + 256 * 256;
  // vT lives in d_out (100.7 MB needed; out is 176.2 MB and dead until gemm2)
  __hip_bfloat16* vT = (__hip_bfloat16*)d_out;

  cvt_x<<<1024, 256, 0, stream>>>((const float4*)x, (ushort4*)reg2, 172032 * 256 / 4);
  prep_k<<<3364, 256, 0, stream>>>(Wqkv, Wproj, btab, relidx, WqkvT, WprojT, biasC, vT, qkv);
  gemm_bt<0><<<dim3(1344, 6), 256, 0, stream>>>(reg2, WqkvT, bqkv, qkv, vT);
  attn_k<<<dim3(2048, 2), 256, 0, stream>>>(qkv, biasC, vT, reg2);
  gemm_bt<1><<<dim3(1344, 2), 256, 0, stream>>>(reg2, WprojT, bproj, out, nullptr);
}

// Round 3
// 862.438 us; speedup vs baseline: 1.0749x; 1.0035x over previous
//
#include <hip/hip_runtime.h>
#include <hip/hip_bf16.h>

typedef __attribute__((ext_vector_type(4))) float f32x4;
typedef __attribute__((ext_vector_type(8))) short bf16x8;

#define GL2LDS16(g, l) __builtin_amdgcn_global_load_lds(                     \
    (const __attribute__((address_space(1))) void*)(g),                      \
    (__attribute__((address_space(3))) void*)(l), 16, 0, 0)

__device__ __forceinline__ unsigned short f2b(float f) {
  __hip_bfloat16 h = __float2bfloat16(f);
  return *reinterpret_cast<unsigned short*>(&h);
}

// ---------------- cvt: x fp32 -> bf16 (vectorized) --------------------------
__global__ __launch_bounds__(256) void cvt_x(
    const float4* __restrict__ x, ushort4* __restrict__ xb, int n4)
{
  for (int i = blockIdx.x * 256 + threadIdx.x; i < n4; i += gridDim.x * 256) {
    float4 v = x[i];
    ushort4 o;
    o.x = f2b(v.x); o.y = f2b(v.y); o.z = f2b(v.z); o.w = f2b(v.w);
    xb[i] = o;
  }
}

// ---------------- prep: transpose weights + pads ----------------------------
// Zeroes vT tok-pads (84..95) and qkv pad rows (172032..172047).
__global__ __launch_bounds__(256) void prep_k(
    const float* __restrict__ Wqkv,    // [256][768] fp32
    const float* __restrict__ Wproj,   // [256][256] fp32
    __hip_bfloat16* __restrict__ WqkvT,   // [768][256] bf16
    __hip_bfloat16* __restrict__ WprojT,  // [256][256] bf16
    __hip_bfloat16* __restrict__ vT,      // [2048*8*32][96] bf16
    __hip_bfloat16* __restrict__ qkvp)    // qkv buffer (for pad-row zeroing)
{
  int idx = blockIdx.x * 256 + threadIdx.x;
  if (idx < 196608) {
    int n = idx >> 8, k = idx & 255;
    WqkvT[idx] = __float2bfloat16(Wqkv[k * 768 + n]);
  } else if (idx < 262144) {
    int i = idx - 196608;
    int n = i >> 8, k = i & 255;
    WprojT[i] = __float2bfloat16(Wproj[k * 256 + n]);
  } else if (idx < 786432) {
    // zero vT tok-pads 84..95 for every (b,h,d) row (stride 96)
    size_t i = idx - 262144;              // [0, 524288)
    __hip_bfloat16* p = vT + i * 96;
    *(ushort4*)(p + 84) = make_ushort4(0, 0, 0, 0);        // elems 84..87 (8B)
    *(uint4*)(p + 88) = make_uint4(0, 0, 0, 0);            // elems 88..95 (16B)
  } else if (idx < 787456) {
    // zero qkv pad rows 172032..172047 (8192 elems, 16B per thread)
    size_t i = idx - 786432;              // [0, 1024)
    *(uint4*)(qkvp + (size_t)172032 * 512 + i * 8) = make_uint4(0, 0, 0, 0);
  }
}

// ---------------- GEMM: C[M][N] = A[M][256] @ Bt[N][256]^T + bias ----------
// m97 structure: 128x128 block tile, 4 waves of 4x4 16x16 tiles, BK=32,
// global_load_lds width-16 staging (wave-uniform LDS base + lane*16).
// MODE 0: A row-major 256 (xb); out = qkv512 (cols<512, bf16) + vT redirect
//         (cols>=512 -> vT[b*256 + (col-512)][96] at tok=row%84, 8B packed).
// MODE 1: A head-major [kk][172032][32] (attn out); out fp32 row-major 256.
template <int MODE>
__global__ __launch_bounds__(256, 2) void gemm_bt(
    const __hip_bfloat16* __restrict__ A,
    const __hip_bfloat16* __restrict__ Bt,
    const float* __restrict__ bias,
    void* __restrict__ Cv,
    __hip_bfloat16* __restrict__ vT)
{
  __shared__ __align__(16) __hip_bfloat16 As[128 * 32];
  __shared__ __align__(16) __hip_bfloat16 Bs[128 * 32];
  const int t = threadIdx.x;
  const int w = t >> 6, lane = t & 63;
  const int lane15 = lane & 15, quad = lane >> 4;
  const int m0 = blockIdx.x * 128, n0 = blockIdx.y * 128;
  const int wm = (w >> 1) * 64, wn = (w & 1) * 64;
  const int srow = w * 16 + (lane >> 2);   // staged row within 64-row half
  const int scol = (lane & 3) * 8;         // element offset within 32-wide K slab
  const __hip_bfloat16* gA = A + (size_t)(m0 + srow) * 256 + scol;
  const __hip_bfloat16* gB = Bt + (size_t)(n0 + srow) * 256 + scol;
  __hip_bfloat16* lA = As + w * 16 * 32;   // wave-uniform LDS base
  __hip_bfloat16* lB = Bs + w * 16 * 32;
  f32x4 acc[4][4] = {};
#pragma unroll 1
  for (int kk = 0; kk < 8; ++kk) {
    if (MODE == 0) {
      GL2LDS16(gA + kk * 32, lA);
      GL2LDS16(gA + 64 * 256 + kk * 32, lA + 64 * 32);
    } else {
      const __hip_bfloat16* gAk = A + ((size_t)kk * 172032 + m0 + srow) * 32 + scol;
      GL2LDS16(gAk, lA);
      GL2LDS16(gAk + 64 * 32, lA + 64 * 32);
    }
    GL2LDS16(gB + kk * 32, lB);
    GL2LDS16(gB + 64 * 256 + kk * 32, lB + 64 * 32);
    __syncthreads();  // compiler inserts vmcnt(0) drain before barrier
    bf16x8 af[4], bfr[4];
#pragma unroll
    for (int i = 0; i < 4; ++i)
      af[i] = *(const bf16x8*)(As + (wm + i * 16 + lane15) * 32 + quad * 8);
#pragma unroll
    for (int j = 0; j < 4; ++j)
      bfr[j] = *(const bf16x8*)(Bs + (wn + j * 16 + lane15) * 32 + quad * 8);
#pragma unroll
    for (int i = 0; i < 4; ++i)
#pragma unroll
      for (int j = 0; j < 4; ++j)
        acc[i][j] = __builtin_amdgcn_mfma_f32_16x16x32_bf16(af[i], bfr[j], acc[i][j], 0, 0, 0);
    __syncthreads();
  }
  if (MODE == 1) {
#pragma unroll
    for (int j = 0; j < 4; ++j) {
      const int col = n0 + wn + j * 16 + lane15;
      const float bv = bias[col];
#pragma unroll
      for (int i = 0; i < 4; ++i) {
        const int row = m0 + wm + i * 16 + quad * 4;
#pragma unroll
        for (int r = 0; r < 4; ++r)
          ((float*)Cv)[(size_t)(row + r) * 256 + col] = acc[i][j][r] + bv;
      }
    }
  } else if (blockIdx.y < 4) {
    // q,k columns -> qkv buffer, stride 512
#pragma unroll
    for (int j = 0; j < 4; ++j) {
      const int col = n0 + wn + j * 16 + lane15;
      const float bv = bias[col];
#pragma unroll
      for (int i = 0; i < 4; ++i) {
        const int row = m0 + wm + i * 16 + quad * 4;
#pragma unroll
        for (int r = 0; r < 4; ++r)
          ((__hip_bfloat16*)Cv)[(size_t)(row + r) * 512 + col] = __float2bfloat16(acc[i][j][r] + bv);
      }
    }
  } else {
    // v columns -> transposed vT[b*256 + cd][96] at tok. The 4 r-values are
    // 4 consecutive tokens (84%4==0 => never straddle a batch boundary), so
    // pack them into one 8B store: 4x fewer scatter stores, 32B-contiguous
    // across the 4 quads of a lane15 group.
#pragma unroll
    for (int j = 0; j < 4; ++j) {
      const int col = n0 + wn + j * 16 + lane15;
      const float bv = bias[col];
      const int cd = col - 512;  // h*32+d in [0,256)
#pragma unroll
      for (int i = 0; i < 4; ++i) {
        const int rowb = m0 + wm + i * 16 + quad * 4;
        const unsigned bq = (unsigned)rowb / 84u;   // magic-mul (const divisor)
        const unsigned tokb = (unsigned)rowb - bq * 84u;
        ushort4 pk;
        pk.x = f2b(acc[i][j][0] + bv);
        pk.y = f2b(acc[i][j][1] + bv);
        pk.z = f2b(acc[i][j][2] + bv);
        pk.w = f2b(acc[i][j][3] + bv);
        *(ushort4*)(vT + ((size_t)bq * 256 + cd) * 96 + tokb) = pk;
      }
    }
  }
}

// ---------------- fused attention (softmax(QK^T*s + bias) @ V) -------------
// v4: grid (2048,2); wave w handles head h = w + 4*blockIdx.y.
// - Bias computed on the fly: rel_index is separable (idx = f(row)+g(col)),
//   so each wave stages its head's 207-entry f32 bias_table column into LDS
//   once; the softmax inner loop does conflict-free ds_read_b32 instead of
//   L2-missing global loads (removes ~300 MB of mid-loop FETCH traffic).
// - O stores go through a stride-36 LDS transpose slab -> one 16B store per
//   lane per mt (full 64B sectors, no partial-line write amplification).
__global__ __launch_bounds__(256, 5) void attn_k(
    const __hip_bfloat16* __restrict__ qkv,    // [172048][512] q,k (pad rows zeroed)
    const float* __restrict__ btab,            // [207][8] fp32
    const __hip_bfloat16* __restrict__ vT,     // [2048*8*32][96]
    __hip_bfloat16* __restrict__ aout)         // [8][172032][32] head-major
{
  __shared__ __align__(16) __hip_bfloat16 Pb[4][16 * 104];
  __shared__ __align__(16) __hip_bfloat16 Ob[4][16 * 36];
  __shared__ __align__(16) float btabL[4][208];
  const int b = blockIdx.x;
  const int t = threadIdx.x;
  const int w = t >> 6, lane = t & 63;
  const int lane15 = lane & 15, quad = lane >> 4;
  const int h = w + 4 * blockIdx.y;
  const __hip_bfloat16* base = qkv + (size_t)b * (84 * 512);
  __hip_bfloat16* Pw = Pb[w];
  __hip_bfloat16* Ow = Ob[w];
  float* btw = btabL[w];
  const float scale = 0.10910894511799619f;  // 84^-0.5

  // stage this wave's head column of bias_table into LDS (per-wave, no sync)
#pragma unroll
  for (int tt = 0; tt < 4; ++tt) {
    int e = lane + tt * 64;
    if (e < 207) btw[e] = btab[e * 8 + h];
  }

  // Q/K fragments: contiguous 16B chunks straight from global
  bf16x8 qa[6], kb[6], vb[3][2];
#pragma unroll
  for (int i = 0; i < 6; ++i)
    qa[i] = *(const bf16x8*)(base + (size_t)(i * 16 + lane15) * 512 + h * 32 + quad * 8);
#pragma unroll
  for (int j = 0; j < 6; ++j)
    kb[j] = *(const bf16x8*)(base + (size_t)(j * 16 + lane15) * 512 + 256 + h * 32 + quad * 8);
  // V^T fragments straight from vT (tok pads 84..95 are zeroed)
  const __hip_bfloat16* vbase = vT + (size_t)(b * 256 + h * 32) * 96;
#pragma unroll
  for (int kk = 0; kk < 3; ++kk) {
    vb[kk][0] = *(const bf16x8*)(vbase + (size_t)lane15 * 96 + kk * 32 + quad * 8);
    vb[kk][1] = *(const bf16x8*)(vbase + (size_t)(16 + lane15) * 96 + kk * 32 + quad * 8);
  }

  // per-lane column index terms: g(col) = 83-col + (col<64?20:col<80?4:0)
  int gidx[6];
  bool pad[6];
#pragma unroll
  for (int ct = 0; ct < 6; ++ct) {
    int col = ct * 16 + lane15;
    int offw = (col < 64) ? 20 : ((col < 80) ? 4 : 0);
    int g = 83 - col + offw;
    pad[ct] = (col >= 84);
    gidx[ct] = g < 0 ? 0 : g;
  }

#pragma unroll 1
  for (int mt = 0; mt < 6; ++mt) {
    // QK^T row-block: 6 independent MFMAs (head_dim 32 = single K step)
    f32x4 S[6] = {};
#pragma unroll
    for (int ct = 0; ct < 6; ++ct)
      S[ct] = __builtin_amdgcn_mfma_f32_16x16x32_bf16(qa[mt], kb[ct], S[ct], 0, 0, 0);

    // f(row) = row + (row<64?0:row<80?4:20), clamped for pad rows (discarded)
    int fr[4];
#pragma unroll
    for (int r = 0; r < 4; ++r) {
      int row = mt * 16 + quad * 4 + r;
      int rc = row > 83 ? 83 : row;
      fr[r] = rc + ((rc < 64) ? 0 : ((rc < 80) ? 4 : 20));
    }

    // softmax: a row of S spans the 16 lanes of a quad-group (col=lane&15)
    f32x4 mx = {-3.0e38f, -3.0e38f, -3.0e38f, -3.0e38f};
#pragma unroll
    for (int ct = 0; ct < 6; ++ct) {
      f32x4 tv;
#pragma unroll
      for (int r = 0; r < 4; ++r) {
        float bv = btw[fr[r] + gidx[ct]];
        bv = pad[ct] ? -1e30f : bv;
        tv[r] = S[ct][r] * scale + bv;
      }
      S[ct] = tv;
      mx[0] = fmaxf(mx[0], tv[0]); mx[1] = fmaxf(mx[1], tv[1]);
      mx[2] = fmaxf(mx[2], tv[2]); mx[3] = fmaxf(mx[3], tv[3]);
    }
#pragma unroll
    for (int off = 1; off < 16; off <<= 1) {
#pragma unroll
      for (int r = 0; r < 4; ++r)
        mx[r] = fmaxf(mx[r], __shfl_xor(mx[r], off, 64));
    }
    f32x4 sm = {0.f, 0.f, 0.f, 0.f};
#pragma unroll
    for (int ct = 0; ct < 6; ++ct) {
#pragma unroll
      for (int r = 0; r < 4; ++r) {
        float p = __expf(S[ct][r] - mx[r]);
        sm[r] += p;
        // C-layout -> row-major P~ slab in per-wave LDS (A-operand for PV)
        Pw[(quad * 4 + r) * 104 + ct * 16 + lane15] = __float2bfloat16(p);
      }
    }
#pragma unroll
    for (int off = 1; off < 16; off <<= 1) {
#pragma unroll
      for (int r = 0; r < 4; ++r)
        sm[r] += __shfl_xor(sm[r], off, 64);
    }
    f32x4 inv;
    inv[0] = 1.0f / sm[0]; inv[1] = 1.0f / sm[1];
    inv[2] = 1.0f / sm[2]; inv[3] = 1.0f / sm[3];

    // P~ @ V for this row-block (K = 96 over 3 slabs of 32)
    f32x4 O0 = {}, O1 = {};
#pragma unroll
    for (int kk = 0; kk < 3; ++kk) {
      bf16x8 pa = *(const bf16x8*)(Pw + lane15 * 104 + kk * 32 + quad * 8);
      O0 = __builtin_amdgcn_mfma_f32_16x16x32_bf16(pa, vb[kk][0], O0, 0, 0, 0);
      O1 = __builtin_amdgcn_mfma_f32_16x16x32_bf16(pa, vb[kk][1], O1, 0, 0, 0);
    }
    // normalize -> LDS transpose slab (stride 36: conflict-free writes)
#pragma unroll
    for (int r = 0; r < 4; ++r) {
      Ow[(quad * 4 + r) * 36 + lane15]      = __float2bfloat16(O0[r] * inv[r]);
      Ow[(quad * 4 + r) * 36 + lane15 + 16] = __float2bfloat16(O1[r] * inv[r]);
    }
    // read back 16B/lane, store full sectors (rows < 84 only)
    {
      int rrow = lane >> 2;                 // 0..15
      int row = mt * 16 + rrow;
      bf16x8 ov = *(const bf16x8*)(Ow + rrow * 36 + (lane & 3) * 8);
      if (row < 84) {
        size_t o = ((size_t)h * 172032 + (size_t)b * 84 + row) * 32 + (lane & 3) * 8;
        *(bf16x8*)(aout + o) = ov;
      }
    }
  }
}

// ---------------------------------------------------------------------------
extern "C" void kernel_launch(void* const* d_in, const int* in_sizes, int n_in,
                              void* d_out, int out_size, void* d_ws, size_t ws_size,
                              hipStream_t stream) {
  const float* x     = (const float*)d_in[0];
  const float* Wqkv  = (const float*)d_in[1];
  const float* bqkv  = (const float*)d_in[2];
  const float* Wproj = (const float*)d_in[3];
  const float* bproj = (const float*)d_in[4];
  const float* btab  = (const float*)d_in[5];
  float* out = (float*)d_out;

  char* ws = (char*)d_ws;
  const size_t QKV_BYTES  = (size_t)172048 * 512 * 2;   // 176,177,152 (q,k only + pad rows)
  const size_t REG2_BYTES = (size_t)172032 * 256 * 2;   //  88,080,384 (xb then aout head-major)
  const size_t SMALL_BYTES = (size_t)(768 * 256 + 256 * 256) * 2;
  if (ws_size < QKV_BYTES + REG2_BYTES + SMALL_BYTES) return;

  __hip_bfloat16* qkv  = (__hip_bfloat16*)ws;
  __hip_bfloat16* reg2 = (__hip_bfloat16*)(ws + QKV_BYTES);   // xb during GEMM-1, aout after
  __hip_bfloat16* WqkvT  = (__hip_bfloat16*)(ws + QKV_BYTES + REG2_BYTES);
  __hip_bfloat16* WprojT = WqkvT + 768 * 256;
  // vT lives in d_out (100.7 MB needed; out is 176.2 MB and dead until gemm2)
  __hip_bfloat16* vT = (__hip_bfloat16*)d_out;

  cvt_x<<<1024, 256, 0, stream>>>((const float4*)x, (ushort4*)reg2, 172032 * 256 / 4);
  prep_k<<<3076, 256, 0, stream>>>(Wqkv, Wproj, WqkvT, WprojT, vT, qkv);
  gemm_bt<0><<<dim3(1344, 6), 256, 0, stream>>>(reg2, WqkvT, bqkv, qkv, vT);
  attn_k<<<dim3(2048, 2), 256, 0, stream>>>(qkv, btab, vT, reg2);
  gemm_bt<1><<<dim3(1344, 2), 256, 0, stream>>>(reg2, WprojT, bproj, out, nullptr);
}

// Round 5
// 607.962 us; speedup vs baseline: 1.5248x; 1.4186x over previous
//
#include <hip/hip_runtime.h>
#include <hip/hip_bf16.h>

typedef __attribute__((ext_vector_type(4))) float f32x4;
typedef __attribute__((ext_vector_type(8))) short bf16x8;

#define GL2LDS16(g, l) __builtin_amdgcn_global_load_lds(                     \
    (const __attribute__((address_space(1))) void*)(g),                      \
    (__attribute__((address_space(3))) void*)(l), 16, 0, 0)

__device__ __forceinline__ unsigned short f2b(float f) {
  __hip_bfloat16 h = __float2bfloat16(f);
  return *reinterpret_cast<unsigned short*>(&h);
}

// ---------------- cvt: x fp32 -> bf16 (vectorized) --------------------------
__global__ __launch_bounds__(256) void cvt_x(
    const float4* __restrict__ x, ushort4* __restrict__ xb, int n4)
{
  for (int i = blockIdx.x * 256 + threadIdx.x; i < n4; i += gridDim.x * 256) {
    float4 v = x[i];
    ushort4 o;
    o.x = f2b(v.x); o.y = f2b(v.y); o.z = f2b(v.z); o.w = f2b(v.w);
    xb[i] = o;
  }
}

// ---------------- prep: transpose weights + pads ----------------------------
// Zeroes vT tok-pads (84..95) and qT/kT per-head pad rows (172032..172047).
__global__ __launch_bounds__(256) void prep_k(
    const float* __restrict__ Wqkv,    // [256][768] fp32
    const float* __restrict__ Wproj,   // [256][256] fp32
    __hip_bfloat16* __restrict__ WqkvT,   // [768][256] bf16
    __hip_bfloat16* __restrict__ WprojT,  // [256][256] bf16
    __hip_bfloat16* __restrict__ vT,      // [2048*8*32][96] bf16
    __hip_bfloat16* __restrict__ qT,      // [8][172048][32] bf16
    __hip_bfloat16* __restrict__ kT)      // [8][172048][32] bf16
{
  int idx = blockIdx.x * 256 + threadIdx.x;
  if (idx < 196608) {
    int n = idx >> 8, k = idx & 255;
    WqkvT[idx] = __float2bfloat16(Wqkv[k * 768 + n]);
  } else if (idx < 262144) {
    int i = idx - 196608;
    int n = i >> 8, k = i & 255;
    WprojT[i] = __float2bfloat16(Wproj[k * 256 + n]);
  } else if (idx < 786432) {
    // zero vT tok-pads 84..95 for every (b,h,d) row (stride 96)
    size_t i = idx - 262144;              // [0, 524288)
    __hip_bfloat16* p = vT + i * 96;
    *(ushort4*)(p + 84) = make_ushort4(0, 0, 0, 0);        // elems 84..87 (8B)
    *(uint4*)(p + 88) = make_uint4(0, 0, 0, 0);            // elems 88..95 (16B)
  } else if (idx < 787456) {
    // zero qT/kT pad rows 172032..172047 per head (8 heads x 16 rows x 32)
    int i = idx - 786432;                 // [0, 1024)
    __hip_bfloat16* buf = (i < 512) ? qT : kT;
    int ii = i & 511;
    int head = ii >> 6, rem = ii & 63;    // 64 threads/head, 8 elems each
    *(uint4*)(buf + ((size_t)head * 172048 + 172032) * 32 + rem * 8) =
        make_uint4(0, 0, 0, 0);
  }
}

// ---------------- GEMM: C[M][N] = A[M][256] @ Bt[N][256]^T + bias ----------
// m97 structure: 128x128 block tile, 4 waves of 4x4 16x16 tiles, BK=32,
// global_load_lds width-16 staging (wave-uniform LDS base + lane*16).
// MODE 0 (qkv): blockIdx.y 0-1 -> q cols -> qT head-major via LDS transpose;
//               y 2-3 -> k cols -> kT likewise; y 4-5 -> v -> vT [d][tok].
// MODE 1: A head-major [h][172032][32] (attn out); out fp32 row-major 256.
template <int MODE>
__global__ __launch_bounds__(256, 2) void gemm_bt(
    const __hip_bfloat16* __restrict__ A,
    const __hip_bfloat16* __restrict__ Bt,
    const float* __restrict__ bias,
    void* __restrict__ Cv,
    __hip_bfloat16* __restrict__ qT,
    __hip_bfloat16* __restrict__ kT,
    __hip_bfloat16* __restrict__ vT)
{
  __shared__ __align__(16) __hip_bfloat16 Smem[2 * 128 * 32];
  __hip_bfloat16* As = Smem;
  __hip_bfloat16* Bs = Smem + 128 * 32;
  const int t = threadIdx.x;
  const int w = t >> 6, lane = t & 63;
  const int lane15 = lane & 15, quad = lane >> 4;
  const int m0 = blockIdx.x * 128, n0 = blockIdx.y * 128;
  const int wm = (w >> 1) * 64, wn = (w & 1) * 64;
  const int srow = w * 16 + (lane >> 2);   // staged row within 64-row half
  const int scol = (lane & 3) * 8;         // element offset within 32-wide K slab
  const __hip_bfloat16* gA = A + (size_t)(m0 + srow) * 256 + scol;
  const __hip_bfloat16* gB = Bt + (size_t)(n0 + srow) * 256 + scol;
  __hip_bfloat16* lA = As + w * 16 * 32;   // wave-uniform LDS base
  __hip_bfloat16* lB = Bs + w * 16 * 32;
  f32x4 acc[4][4] = {};
#pragma unroll 1
  for (int kk = 0; kk < 8; ++kk) {
    if (MODE == 0) {
      GL2LDS16(gA + kk * 32, lA);
      GL2LDS16(gA + 64 * 256 + kk * 32, lA + 64 * 32);
    } else {
      const __hip_bfloat16* gAk = A + ((size_t)kk * 172032 + m0 + srow) * 32 + scol;
      GL2LDS16(gAk, lA);
      GL2LDS16(gAk + 64 * 32, lA + 64 * 32);
    }
    GL2LDS16(gB + kk * 32, lB);
    GL2LDS16(gB + 64 * 256 + kk * 32, lB + 64 * 32);
    __syncthreads();  // compiler inserts vmcnt(0) drain before barrier
    bf16x8 af[4], bfr[4];
#pragma unroll
    for (int i = 0; i < 4; ++i)
      af[i] = *(const bf16x8*)(As + (wm + i * 16 + lane15) * 32 + quad * 8);
#pragma unroll
    for (int j = 0; j < 4; ++j)
      bfr[j] = *(const bf16x8*)(Bs + (wn + j * 16 + lane15) * 32 + quad * 8);
#pragma unroll
    for (int i = 0; i < 4; ++i)
#pragma unroll
      for (int j = 0; j < 4; ++j)
        acc[i][j] = __builtin_amdgcn_mfma_f32_16x16x32_bf16(af[i], bfr[j], acc[i][j], 0, 0, 0);
    __syncthreads();
  }
  if (MODE == 1) {
#pragma unroll
    for (int j = 0; j < 4; ++j) {
      const int col = n0 + wn + j * 16 + lane15;
      const float bv = bias[col];
#pragma unroll
      for (int i = 0; i < 4; ++i) {
        const int row = m0 + wm + i * 16 + quad * 4;
#pragma unroll
        for (int r = 0; r < 4; ++r)
          ((float*)Cv)[(size_t)(row + r) * 256 + col] = acc[i][j][r] + bv;
      }
    }
  } else if (blockIdx.y < 4) {
    // q/k columns -> head-major [h][172048][32] via per-wave LDS transpose.
    // Wave tile = 64 rows x 64 cols (2 heads). 4 sub-passes of 32 rows x 32
    // cols (head p, row-half i2): stage to LDS slab (stride 34, bank-spread),
    // read back 16B/lane, store 1KB-contiguous rows.
    __hip_bfloat16* dst = (blockIdx.y < 2) ? qT : kT;
    const int coff = (blockIdx.y < 2) ? 0 : 256;
    __hip_bfloat16* slab = Smem + w * 1088;   // 32x34 elems = 2176B per wave
#pragma unroll
    for (int p = 0; p < 2; ++p) {
      const int hh = (n0 + wn + 32 * p - coff) >> 5;   // head index 0..7
#pragma unroll
      for (int i2 = 0; i2 < 2; ++i2) {
#pragma unroll
        for (int i = 2 * i2; i < 2 * i2 + 2; ++i)
#pragma unroll
          for (int j = 2 * p; j < 2 * p + 2; ++j) {
            const int col = n0 + wn + j * 16 + lane15;
            const float bv = bias[col];
#pragma unroll
            for (int r = 0; r < 4; ++r)
              slab[((i & 1) * 16 + quad * 4 + r) * 34 + (j & 1) * 16 + lane15] =
                  __float2bfloat16(acc[i][j][r] + bv);
          }
#pragma unroll
        for (int tt = 0; tt < 2; ++tt) {
          const int lrow = tt * 16 + (lane >> 2);        // 0..31
          bf16x8 v = *(const bf16x8*)(slab + lrow * 34 + (lane & 3) * 8);
          const int grow = m0 + wm + i2 * 32 + lrow;     // token-row
          *(bf16x8*)(dst + ((size_t)hh * 172048 + grow) * 32 + (lane & 3) * 8) = v;
        }
      }
    }
  } else {
    // v columns -> transposed vT[b*256 + cd][96] at tok, 8B-packed stores
#pragma unroll
    for (int j = 0; j < 4; ++j) {
      const int col = n0 + wn + j * 16 + lane15;
      const float bv = bias[col];
      const int cd = col - 512;  // h*32+d in [0,256)
#pragma unroll
      for (int i = 0; i < 4; ++i) {
        const int rowb = m0 + wm + i * 16 + quad * 4;
        const unsigned bq = (unsigned)rowb / 84u;   // magic-mul (const divisor)
        const unsigned tokb = (unsigned)rowb - bq * 84u;
        ushort4 pk;
        pk.x = f2b(acc[i][j][0] + bv);
        pk.y = f2b(acc[i][j][1] + bv);
        pk.z = f2b(acc[i][j][2] + bv);
        pk.w = f2b(acc[i][j][3] + bv);
        *(ushort4*)(vT + ((size_t)bq * 256 + cd) * 96 + tokb) = pk;
      }
    }
  }
}

// ---------------- fused attention (softmax(QK^T*s + bias) @ V) -------------
// v5: head-major q/k. kb[6]+vb[6] fragments persistent in VGPRs (launch
// bounds (256,4) gives the 128-reg budget; v4's (256,5)/48-VGPR build
// rematerialized these loads EVERY mt iteration -> 2.7x HBM fetch + mid-loop
// L2/L3-miss stalls = the whole bottleneck). qa streamed with 1-ahead
// prefetch. All q/k fragment loads are 1KB-contiguous now.
__global__ __launch_bounds__(256, 4) void attn_k(
    const __hip_bfloat16* __restrict__ qT,     // [8][172048][32] (pad rows zeroed)
    const __hip_bfloat16* __restrict__ kT,     // [8][172048][32]
    const float* __restrict__ btab,            // [207][8] fp32
    const __hip_bfloat16* __restrict__ vT,     // [2048*8*32][96]
    __hip_bfloat16* __restrict__ aout)         // [8][172032][32] head-major
{
  __shared__ __align__(16) __hip_bfloat16 Pb[4][16 * 104];
  __shared__ __align__(16) __hip_bfloat16 Ob[4][16 * 36];
  __shared__ __align__(16) float btabL[4][208];
  const int b = blockIdx.x;
  const int t = threadIdx.x;
  const int w = t >> 6, lane = t & 63;
  const int lane15 = lane & 15, quad = lane >> 4;
  const int h = w + 4 * blockIdx.y;
  __hip_bfloat16* Pw = Pb[w];
  __hip_bfloat16* Ow = Ob[w];
  float* btw = btabL[w];
  const float scale = 0.10910894511799619f;  // 84^-0.5

  const __hip_bfloat16* baseq = qT + ((size_t)h * 172048 + (size_t)b * 84) * 32;
  const __hip_bfloat16* basek = kT + ((size_t)h * 172048 + (size_t)b * 84) * 32;

  // stage this wave's head column of bias_table into LDS (per-wave, no sync)
#pragma unroll
  for (int tt = 0; tt < 4; ++tt) {
    int e = lane + tt * 64;
    if (e < 207) btw[e] = btab[e * 8 + h];
  }

  // K fragments (persistent, contiguous 1KB per fragment)
  bf16x8 kb[6], vb[3][2];
#pragma unroll
  for (int j = 0; j < 6; ++j)
    kb[j] = *(const bf16x8*)(basek + (j * 16 + lane15) * 32 + quad * 8);
  // V^T fragments straight from vT (tok pads 84..95 are zeroed)
  const __hip_bfloat16* vbase = vT + (size_t)(b * 256 + h * 32) * 96;
#pragma unroll
  for (int kk = 0; kk < 3; ++kk) {
    vb[kk][0] = *(const bf16x8*)(vbase + (size_t)lane15 * 96 + kk * 32 + quad * 8);
    vb[kk][1] = *(const bf16x8*)(vbase + (size_t)(16 + lane15) * 96 + kk * 32 + quad * 8);
  }

  // per-lane column index terms: g(col) = 83-col + (col<64?20:col<80?4:0)
  int gidx[6];
  bool pad[6];
#pragma unroll
  for (int ct = 0; ct < 6; ++ct) {
    int col = ct * 16 + lane15;
    int offw = (col < 64) ? 20 : ((col < 80) ? 4 : 0);
    int g = 83 - col + offw;
    pad[ct] = (col >= 84);
    gidx[ct] = g < 0 ? 0 : g;
  }

  // q streamed with one-ahead prefetch (2 live fragments, not 6)
  bf16x8 qa_cur = *(const bf16x8*)(baseq + lane15 * 32 + quad * 8);
#pragma unroll 1
  for (int mt = 0; mt < 6; ++mt) {
    bf16x8 qa_nxt;
    if (mt < 5)
      qa_nxt = *(const bf16x8*)(baseq + ((mt + 1) * 16 + lane15) * 32 + quad * 8);
    // QK^T row-block: 6 independent MFMAs (head_dim 32 = single K step)
    f32x4 S[6] = {};
#pragma unroll
    for (int ct = 0; ct < 6; ++ct)
      S[ct] = __builtin_amdgcn_mfma_f32_16x16x32_bf16(qa_cur, kb[ct], S[ct], 0, 0, 0);

    // f(row) = row + (row<64?0:row<80?4:20), clamped for pad rows (discarded)
    int fr[4];
#pragma unroll
    for (int r = 0; r < 4; ++r) {
      int row = mt * 16 + quad * 4 + r;
      int rc = row > 83 ? 83 : row;
      fr[r] = rc + ((rc < 64) ? 0 : ((rc < 80) ? 4 : 20));
    }

    // softmax: a row of S spans the 16 lanes of a quad-group (col=lane&15)
    f32x4 mx = {-3.0e38f, -3.0e38f, -3.0e38f, -3.0e38f};
#pragma unroll
    for (int ct = 0; ct < 6; ++ct) {
      f32x4 tv;
#pragma unroll
      for (int r = 0; r < 4; ++r) {
        float bv = btw[fr[r] + gidx[ct]];
        bv = pad[ct] ? -1e30f : bv;
        tv[r] = S[ct][r] * scale + bv;
      }
      S[ct] = tv;
      mx[0] = fmaxf(mx[0], tv[0]); mx[1] = fmaxf(mx[1], tv[1]);
      mx[2] = fmaxf(mx[2], tv[2]); mx[3] = fmaxf(mx[3], tv[3]);
    }
#pragma unroll
    for (int off = 1; off < 16; off <<= 1) {
#pragma unroll
      for (int r = 0; r < 4; ++r)
        mx[r] = fmaxf(mx[r], __shfl_xor(mx[r], off, 64));
    }
    f32x4 sm = {0.f, 0.f, 0.f, 0.f};
#pragma unroll
    for (int ct = 0; ct < 6; ++ct) {
#pragma unroll
      for (int r = 0; r < 4; ++r) {
        float p = __expf(S[ct][r] - mx[r]);
        sm[r] += p;
        // C-layout -> row-major P~ slab in per-wave LDS (A-operand for PV)
        Pw[(quad * 4 + r) * 104 + ct * 16 + lane15] = __float2bfloat16(p);
      }
    }
#pragma unroll
    for (int off = 1; off < 16; off <<= 1) {
#pragma unroll
      for (int r = 0; r < 4; ++r)
        sm[r] += __shfl_xor(sm[r], off, 64);
    }
    f32x4 inv;
    inv[0] = 1.0f / sm[0]; inv[1] = 1.0f / sm[1];
    inv[2] = 1.0f / sm[2]; inv[3] = 1.0f / sm[3];

    // P~ @ V for this row-block (K = 96 over 3 slabs of 32)
    f32x4 O0 = {}, O1 = {};
#pragma unroll
    for (int kk = 0; kk < 3; ++kk) {
      bf16x8 pa = *(const bf16x8*)(Pw + lane15 * 104 + kk * 32 + quad * 8);
      O0 = __builtin_amdgcn_mfma_f32_16x16x32_bf16(pa, vb[kk][0], O0, 0, 0, 0);
      O1 = __builtin_amdgcn_mfma_f32_16x16x32_bf16(pa, vb[kk][1], O1, 0, 0, 0);
    }
    // normalize -> LDS transpose slab (stride 36: conflict-free writes)
#pragma unroll
    for (int r = 0; r < 4; ++r) {
      Ow[(quad * 4 + r) * 36 + lane15]      = __float2bfloat16(O0[r] * inv[r]);
      Ow[(quad * 4 + r) * 36 + lane15 + 16] = __float2bfloat16(O1[r] * inv[r]);
    }
    // read back 16B/lane, store full sectors (rows < 84 only)
    {
      int rrow = lane >> 2;                 // 0..15
      int row = mt * 16 + rrow;
      bf16x8 ov = *(const bf16x8*)(Ow + rrow * 36 + (lane & 3) * 8);
      if (row < 84) {
        size_t o = ((size_t)h * 172032 + (size_t)b * 84 + row) * 32 + (lane & 3) * 8;
        *(bf16x8*)(aout + o) = ov;
      }
    }
    qa_cur = qa_nxt;
  }
}

// ---------------------------------------------------------------------------
extern "C" void kernel_launch(void* const* d_in, const int* in_sizes, int n_in,
                              void* d_out, int out_size, void* d_ws, size_t ws_size,
                              hipStream_t stream) {
  const float* x     = (const float*)d_in[0];
  const float* Wqkv  = (const float*)d_in[1];
  const float* bqkv  = (const float*)d_in[2];
  const float* Wproj = (const float*)d_in[3];
  const float* bproj = (const float*)d_in[4];
  const float* btab  = (const float*)d_in[5];
  float* out = (float*)d_out;

  char* ws = (char*)d_ws;
  const size_t QK_BYTES   = (size_t)8 * 172048 * 32 * 2;  // 88,088,576 each
  const size_t REG2_BYTES = (size_t)172032 * 256 * 2;     // 88,080,384 (xb then aout)
  const size_t SMALL_BYTES = (size_t)(768 * 256 + 256 * 256) * 2;
  if (ws_size < 2 * QK_BYTES + REG2_BYTES + SMALL_BYTES) return;  // ~264.8 MB

  __hip_bfloat16* qTb  = (__hip_bfloat16*)ws;
  __hip_bfloat16* kTb  = (__hip_bfloat16*)(ws + QK_BYTES);
  __hip_bfloat16* reg2 = (__hip_bfloat16*)(ws + 2 * QK_BYTES);  // xb then aout
  __hip_bfloat16* WqkvT  = (__hip_bfloat16*)(ws + 2 * QK_BYTES + REG2_BYTES);
  __hip_bfloat16* WprojT = WqkvT + 768 * 256;
  // vT lives in d_out (100.7 MB needed; out is 176.2 MB and dead until gemm2)
  __hip_bfloat16* vT = (__hip_bfloat16*)d_out;

  cvt_x<<<1024, 256, 0, stream>>>((const float4*)x, (ushort4*)reg2, 172032 * 256 / 4);
  prep_k<<<3076, 256, 0, stream>>>(Wqkv, Wproj, WqkvT, WprojT, vT, qTb, kTb);
  gemm_bt<0><<<dim3(1344, 6), 256, 0, stream>>>(reg2, WqkvT, bqkv, nullptr, qTb, kTb, vT);
  attn_k<<<dim3(2048, 2), 256, 0, stream>>>(qTb, kTb, btab, vT, reg2);
  gemm_bt<1><<<dim3(1344, 2), 256, 0, stream>>>(reg2, WprojT, bproj, out, nullptr, nullptr, nullptr);
}